// Round 4
// baseline (534.661 us; speedup 1.0000x reference)
//
#include <hip/hip_runtime.h>
#include <hip/hip_bf16.h>
#include <math.h>

#define N_TOK 2048
#define DIM   1024
#define NE    16
#define NH    2048
#define NO    1024

typedef __attribute__((ext_vector_type(8))) short short8;
typedef __attribute__((ext_vector_type(4))) float f32x4;

__device__ __forceinline__ unsigned short f2bf(float f) {
  union { float f; unsigned u; } v; v.f = f;
  unsigned r = v.u + 0x7FFFu + ((v.u >> 16) & 1u);  // RNE
  return (unsigned short)(r >> 16);
}

__device__ __forceinline__ short8 pack8(float4 a, float4 b) {
  short8 r;
  r[0] = (short)f2bf(a.x); r[1] = (short)f2bf(a.y);
  r[2] = (short)f2bf(a.z); r[3] = (short)f2bf(a.w);
  r[4] = (short)f2bf(b.x); r[5] = (short)f2bf(b.y);
  r[6] = (short)f2bf(b.z); r[7] = (short)f2bf(b.w);
  return r;
}

__device__ __forceinline__ unsigned pkbf(float x, float y) {
  float2 f; f.x = x; f.y = y;
  __hip_bfloat162 b = __float22bfloat162_rn(f);     // v_cvt_pk_bf16_f32 (RNE)
  unsigned u; __builtin_memcpy(&u, &b, 4);
  return u;
}
__device__ __forceinline__ short8 cvt8(float4 a, float4 b) {
  union { short8 s; unsigned u[4]; } r;
  r.u[0] = pkbf(a.x, a.y); r.u[1] = pkbf(a.z, a.w);
  r.u[2] = pkbf(b.x, b.y); r.u[3] = pkbf(b.z, b.w);
  return r.s;
}

// async global->LDS, 16B/lane; LDS dest = wave-uniform base + lane*16 (m97/m104)
__device__ __forceinline__ void glds16(const void* g, void* l) {
  __builtin_amdgcn_global_load_lds(
      (const __attribute__((address_space(1))) void*)g,
      (__attribute__((address_space(3))) void*)l, 16, 0, 0);
}

// LDS-only barrier (lgkmcnt(0), vmcnt untouched) for the WAR edge after MFMA.
__device__ __forceinline__ void lds_barrier() {
  __builtin_amdgcn_s_waitcnt(0xC07F);
  __builtin_amdgcn_s_barrier();
}

// ---------------- Router: fp32 in, double accum, top-2 + renorm ----------------
__global__ __launch_bounds__(256) void router_kernel(
    const float* __restrict__ z, const float* __restrict__ rw,
    const float* __restrict__ rb, int* __restrict__ counts,
    int* __restrict__ list, float* __restrict__ tkw) {
  const int n = blockIdx.x;
  const int t = threadIdx.x;
  const int e = t >> 4, sub = t & 15;
  const float* zr = z + (size_t)n * DIM;
  const float* wr = rw + (size_t)e * DIM;
  double acc = 0.0;
#pragma unroll
  for (int i = 0; i < 16; ++i) {
    const int d = i * 64 + sub * 4;
    const float4 zv = *(const float4*)(zr + d);
    const float4 wv = *(const float4*)(wr + d);
    acc += (double)zv.x * wv.x + (double)zv.y * wv.y
         + (double)zv.z * wv.z + (double)zv.w * wv.w;
  }
  acc += __shfl_xor(acc, 8, 16);
  acc += __shfl_xor(acc, 4, 16);
  acc += __shfl_xor(acc, 2, 16);
  acc += __shfl_xor(acc, 1, 16);
  __shared__ double logits[NE];
  if (sub == 0) logits[e] = acc + (double)rb[e];
  __syncthreads();
  if (t == 0) {
    int i0 = -1, i1 = -1; double v0 = -1e300, v1 = -1e300;
    for (int i = 0; i < NE; ++i) {
      const double v = logits[i];
      if (v > v0) { v1 = v0; i1 = i0; v0 = v; i0 = i; }
      else if (v > v1) { v1 = v; i1 = i; }
    }
    const double w0 = 1.0 / (1.0 + exp(v1 - v0));
    tkw[n * 2 + 0] = (float)w0;
    tkw[n * 2 + 1] = (float)(1.0 - w0);
    const int p0 = atomicAdd(&counts[i0], 1); list[i0 * N_TOK + p0] = n * 2;
    const int p1 = atomicAdd(&counts[i1], 1); list[i1 * N_TOK + p1] = n * 2 + 1;
  }
}

// ---------------- fp32 -> bf16 converters ----------------
__global__ __launch_bounds__(256) void convert_z_kernel(
    const float* __restrict__ z, unsigned short* __restrict__ zbf) {
  const int i = (blockIdx.x * 256 + threadIdx.x) * 8;
  const float4 a = *(const float4*)(z + i);
  const float4 b = *(const float4*)(z + i + 4);
  *(short8*)(zbf + i) = pack8(a, b);
}

__global__ __launch_bounds__(256) void convert_w_kernel(
    const float* __restrict__ src, unsigned short* __restrict__ dst) {
  const size_t i = ((size_t)blockIdx.x * 256 + threadIdx.x) * 8;
  const float4 a = *(const float4*)(src + i);
  const float4 b = *(const float4*)(src + i + 4);
  *(short8*)(dst + i) = cvt8(a, b);
}

// =====================================================================
// FAST PATH: weights pre-converted to bf16; m97-structure 128x128 tiles,
// all-bf16 staging (32 KB/step), double-buffered (T3-minimum pipeline):
// stage(t+1) issued BEFORE compute(t); one __syncthreads per K-step whose
// vmcnt(0) drain lands after a full MFMA phase.
// =====================================================================
#define BMF 128
#define BKF 64
#define ASZF (BMF * BKF * 2)   // 16 KB

// Expert-locked XCD decode: bid%8 == e%8; mt fastest -> mt replicas of a
// weight panel are co-resident on one XCD's L2 (r3: FETCH 106->76 MB).
__global__ __launch_bounds__(256, 2) void gemm1_fast(
    const unsigned short* __restrict__ zbf, const unsigned short* __restrict__ w1b,
    const float* __restrict__ b1, const int* __restrict__ counts,
    const int* __restrict__ list, unsigned short* __restrict__ h) {
  const int bid = blockIdx.x;
  const int slot = bid >> 3;
  const int e  = (bid & 7) | ((slot & 1) << 3);
  const int mt = (slot >> 1) & 7;
  const int nt = slot >> 4;               // 0..15
  const int ne = counts[e];
  if (mt * BMF >= ne) return;
  const int t = threadIdx.x;

  __shared__ __align__(16) unsigned char As[2 * ASZF];   // 32 KB
  __shared__ __align__(16) unsigned char Bs[2 * ASZF];   // 32 KB
  __shared__ int ent_s[BMF];
  if (t < BMF) {
    const int idx = mt * BMF + t;
    ent_s[t] = (idx < ne) ? list[e * N_TOK + idx] : -1;
  }
  __syncthreads();

  const int lane = t & 63, w = t >> 6;
  const unsigned short *aP[4], *bP[4];
  unsigned char *aL[4], *bL[4];
  {
    const int l3 = lane >> 3, c7 = lane & 7;
    const unsigned short* bbase = w1b + ((size_t)e * NH + (size_t)nt * 128) * DIM;
#pragma unroll
    for (int p = 0; p < 4; ++p) {
      const int CI = w + 4 * p;           // 16 chunks of 8 rows x 128 B
      const int R = 8 * CI + l3;
      const int c = c7 ^ (R & 7);
      const int en = ent_s[R];
      aP[p] = zbf + (size_t)(en >= 0 ? (en >> 1) : 0) * DIM + c * 8;
      aL[p] = As + CI * 1024;
      bP[p] = bbase + (size_t)R * DIM + c * 8;
      bL[p] = Bs + CI * 1024;
    }
  }
  const int wm = (w & 1) * 64, wn = (w >> 1) * 64;
  const int l15 = lane & 15, quad = lane >> 4;

  f32x4 acc[4][4];
#pragma unroll
  for (int i = 0; i < 4; ++i)
#pragma unroll
    for (int j = 0; j < 4; ++j) acc[i][j] = (f32x4){0.f, 0.f, 0.f, 0.f};

  // prologue: tile 0 -> buffer 0
#pragma unroll
  for (int p = 0; p < 4; ++p) { glds16(aP[p], aL[p]); glds16(bP[p], bL[p]); }
  __syncthreads();

  for (int kt = 0; kt < 16; ++kt) {
    const int cur = kt & 1, nxt = cur ^ 1;
    if (kt + 1 < 16) {                    // stage NEXT before compute (T3)
      const int k1 = (kt + 1) * BKF;
#pragma unroll
      for (int p = 0; p < 4; ++p) {
        glds16(aP[p] + k1, aL[p] + nxt * ASZF);
        glds16(bP[p] + k1, bL[p] + nxt * ASZF);
      }
    }
    const unsigned char* Ac = As + cur * ASZF;
    const unsigned char* Bc = Bs + cur * ASZF;
#pragma unroll
    for (int kk = 0; kk < BKF; kk += 32) {
      short8 af[4], bfr[4];
      const int c0 = (kk >> 3) + quad;
#pragma unroll
      for (int i = 0; i < 4; ++i) {
        const int Ra = wm + i * 16 + l15;
        af[i] = *(const short8*)(Ac + Ra * 128 + ((c0 ^ (Ra & 7)) << 4));
        const int Rb = wn + i * 16 + l15;
        bfr[i] = *(const short8*)(Bc + Rb * 128 + ((c0 ^ (Rb & 7)) << 4));
      }
#pragma unroll
      for (int i = 0; i < 4; ++i)
#pragma unroll
        for (int j = 0; j < 4; ++j)
          acc[i][j] = __builtin_amdgcn_mfma_f32_16x16x32_bf16(af[i], bfr[j], acc[i][j], 0, 0, 0);
    }
    __syncthreads();   // drains stage(t+1) AFTER a full compute phase
  }

  const int r4 = quad * 4;    // C/D: col=lane&15, row=quad*4+reg
#pragma unroll
  for (int i = 0; i < 4; ++i) {
#pragma unroll
    for (int reg = 0; reg < 4; ++reg) {
      const int row = wm + i * 16 + r4 + reg;
      const int en = ent_s[row];
      if (en < 0) continue;
      unsigned short* hrow = h + (size_t)en * NH;
#pragma unroll
      for (int j = 0; j < 4; ++j) {
        const int col = nt * 128 + wn + j * 16 + l15;
        float v = acc[i][j][reg] + b1[e * NH + col];
        v = 0.5f * v * (1.0f + erff(v * 0.70710678118654752f));
        hrow[col] = f2bf(v);
      }
    }
  }
}

// GEMM2 fast: split-K x2 (linear epilogue -> atomicAdd fused combine).
__global__ __launch_bounds__(256, 2) void gemm2_fast(
    const unsigned short* __restrict__ h, const unsigned short* __restrict__ w2b,
    const float* __restrict__ b2, const int* __restrict__ counts,
    const int* __restrict__ list, const float* __restrict__ tkw,
    float* __restrict__ out) {
  const int bid = blockIdx.x;
  const int slot = bid >> 3;
  const int e  = (bid & 7) | ((slot & 1) << 3);
  const int mt = (slot >> 1) & 7;
  const int rest = slot >> 4;             // 0..15
  const int nt = rest & 7;                // 0..7
  const int ks = rest >> 3;               // 0..1 (K half)
  const int ne = counts[e];
  if (mt * BMF >= ne) return;
  const int t = threadIdx.x;

  __shared__ __align__(16) unsigned char As[2 * ASZF];
  __shared__ __align__(16) unsigned char Bs[2 * ASZF];
  __shared__ int ent_s[BMF];
  if (t < BMF) {
    const int idx = mt * BMF + t;
    ent_s[t] = (idx < ne) ? list[e * N_TOK + idx] : -1;
  }
  __syncthreads();

  const int lane = t & 63, w = t >> 6;
  const int kbase = ks * (NH / 2);        // 0 or 1024
  const unsigned short *aP[4], *bP[4];
  unsigned char *aL[4], *bL[4];
  {
    const int l3 = lane >> 3, c7 = lane & 7;
    const unsigned short* bbase = w2b + ((size_t)e * NO + (size_t)nt * 128) * NH + kbase;
#pragma unroll
    for (int p = 0; p < 4; ++p) {
      const int CI = w + 4 * p;
      const int R = 8 * CI + l3;
      const int c = c7 ^ (R & 7);
      const int en = ent_s[R];
      aP[p] = h + (size_t)(en >= 0 ? en : 0) * NH + kbase + c * 8;
      aL[p] = As + CI * 1024;
      bP[p] = bbase + (size_t)R * NH + c * 8;
      bL[p] = Bs + CI * 1024;
    }
  }
  const int wm = (w & 1) * 64, wn = (w >> 1) * 64;
  const int l15 = lane & 15, quad = lane >> 4;

  f32x4 acc[4][4];
#pragma unroll
  for (int i = 0; i < 4; ++i)
#pragma unroll
    for (int j = 0; j < 4; ++j) acc[i][j] = (f32x4){0.f, 0.f, 0.f, 0.f};

#pragma unroll
  for (int p = 0; p < 4; ++p) { glds16(aP[p], aL[p]); glds16(bP[p], bL[p]); }
  __syncthreads();

  for (int kt = 0; kt < 16; ++kt) {       // 16 steps over this K half
    const int cur = kt & 1, nxt = cur ^ 1;
    if (kt + 1 < 16) {
      const int k1 = (kt + 1) * BKF;
#pragma unroll
      for (int p = 0; p < 4; ++p) {
        glds16(aP[p] + k1, aL[p] + nxt * ASZF);
        glds16(bP[p] + k1, bL[p] + nxt * ASZF);
      }
    }
    const unsigned char* Ac = As + cur * ASZF;
    const unsigned char* Bc = Bs + cur * ASZF;
#pragma unroll
    for (int kk = 0; kk < BKF; kk += 32) {
      short8 af[4], bfr[4];
      const int c0 = (kk >> 3) + quad;
#pragma unroll
      for (int i = 0; i < 4; ++i) {
        const int Ra = wm + i * 16 + l15;
        af[i] = *(const short8*)(Ac + Ra * 128 + ((c0 ^ (Ra & 7)) << 4));
        const int Rb = wn + i * 16 + l15;
        bfr[i] = *(const short8*)(Bc + Rb * 128 + ((c0 ^ (Rb & 7)) << 4));
      }
#pragma unroll
      for (int i = 0; i < 4; ++i)
#pragma unroll
        for (int j = 0; j < 4; ++j)
          acc[i][j] = __builtin_amdgcn_mfma_f32_16x16x32_bf16(af[i], bfr[j], acc[i][j], 0, 0, 0);
    }
    __syncthreads();
  }

  const int r4 = quad * 4;
#pragma unroll
  for (int i = 0; i < 4; ++i) {
#pragma unroll
    for (int reg = 0; reg < 4; ++reg) {
      const int row = wm + i * 16 + r4 + reg;
      const int en = ent_s[row];
      if (en < 0) continue;
      const float wgt = tkw[en];
      float* orow = out + (size_t)(en >> 1) * NO;
#pragma unroll
      for (int j = 0; j < 4; ++j) {
        const int col = nt * 128 + wn + j * 16 + l15;
        float v = wgt * acc[i][j][reg];
        if (ks == 0) v += wgt * b2[e * NO + col];
        atomicAdd(&orow[col], v);
      }
    }
  }
}

// =====================================================================
// FALLBACK PATH (ws too small for bf16 weight copies): verbatim r0
// kernels — proven 425 us.
// =====================================================================
#define BM 128
#define BN 128
#define BK 64
#define NNT1 (NH / BN)   // 16
#define NNT2 (NO / BN)   // 8
#define MT_LEVELS 8

__device__ __forceinline__ void decode_bid_fb(int bid, int nent, int& mt, int& ent) {
  if (bid < 2 * nent) {
    mt = (bid >> 3) & 1;
    ent = (bid >> 4) * 8 + (bid & 7);
  } else {
    const int t2 = bid - 2 * nent;
    mt = 2 + t2 / nent;
    ent = t2 - (mt - 2) * nent;
  }
}

__global__ __launch_bounds__(256, 2) void gemm1_fb(
    const unsigned short* __restrict__ zbf, const float* __restrict__ w1,
    const float* __restrict__ b1, const int* __restrict__ counts,
    const int* __restrict__ list, unsigned short* __restrict__ h) {
  int mt, ent;
  decode_bid_fb(blockIdx.x, NE * NNT1, mt, ent);
  const int e  = ent >> 4;
  const int nt = ent & 15;
  const int ne = counts[e];
  if (mt * BM >= ne) return;
  const int t = threadIdx.x;

  __shared__ __align__(16) unsigned char As[BM * BK * 2];
  __shared__ __align__(16) unsigned char Bs[BN * BK * 4];
  __shared__ int ent_s[BM];
  if (t < BM) {
    const int idx = mt * BM + t;
    ent_s[t] = (idx < ne) ? list[e * N_TOK + idx] : -1;
  }
  __syncthreads();

  const int lane = t & 63, w = t >> 6;
  const unsigned short* aP[4];
  const float* bP[8];
  unsigned char *aL[4], *bL[8];
  {
    const int l3 = lane >> 3, c7 = lane & 7;
#pragma unroll
    for (int p = 0; p < 4; ++p) {
      const int CI = w + 4 * p;
      const int R = 8 * CI + l3;
      const int c = c7 ^ (R & 7);
      const int en = ent_s[R];
      aP[p] = zbf + (size_t)(en >= 0 ? (en >> 1) : 0) * DIM + c * 8;
      aL[p] = As + CI * 1024;
    }
    const int l4 = lane >> 4, c15 = lane & 15;
    const float* bbase = w1 + ((size_t)e * NH + (size_t)nt * BN) * DIM;
#pragma unroll
    for (int q = 0; q < 8; ++q) {
      const int CI = w + 4 * q;
      const int R = 4 * CI + l4;
      const int c = c15 ^ (R & 15);
      bP[q] = bbase + (size_t)R * DIM + c * 4;
      bL[q] = Bs + CI * 1024;
    }
  }

  const int wm = (w & 1) * 64, wn = (w >> 1) * 64;
  const int l15 = lane & 15, quad = lane >> 4;

  f32x4 acc[4][4];
#pragma unroll
  for (int i = 0; i < 4; ++i)
#pragma unroll
    for (int j = 0; j < 4; ++j) acc[i][j] = (f32x4){0.f, 0.f, 0.f, 0.f};

  for (int k0 = 0; k0 < DIM; k0 += BK) {
#pragma unroll
    for (int p = 0; p < 4; ++p) glds16(aP[p] + k0, aL[p]);
#pragma unroll
    for (int q = 0; q < 8; ++q) glds16(bP[q] + k0, bL[q]);
    __syncthreads();
#pragma unroll
    for (int kk = 0; kk < BK; kk += 32) {
      short8 af[4], bfr[4];
#pragma unroll
      for (int i = 0; i < 4; ++i) {
        const int R = wm + i * 16 + l15;
        const int c0 = (kk >> 3) + quad;
        af[i] = *(const short8*)(As + R * 128 + ((c0 ^ (R & 7)) << 4));
      }
#pragma unroll
      for (int j = 0; j < 4; ++j) {
        const int R = wn + j * 16 + l15;
        const int c0 = (kk >> 2) + 2 * quad;
        const float4 f0 = *(const float4*)(Bs + R * 256 + ((c0 ^ (R & 15)) << 4));
        const float4 f1 = *(const float4*)(Bs + R * 256 + (((c0 + 1) ^ (R & 15)) << 4));
        bfr[j] = cvt8(f0, f1);
      }
#pragma unroll
      for (int i = 0; i < 4; ++i)
#pragma unroll
        for (int j = 0; j < 4; ++j)
          acc[i][j] = __builtin_amdgcn_mfma_f32_16x16x32_bf16(af[i], bfr[j], acc[i][j], 0, 0, 0);
    }
    lds_barrier();
  }

  const int r4 = quad * 4;
#pragma unroll
  for (int i = 0; i < 4; ++i) {
#pragma unroll
    for (int reg = 0; reg < 4; ++reg) {
      const int row = wm + i * 16 + r4 + reg;
      const int en = ent_s[row];
      if (en < 0) continue;
      unsigned short* hrow = h + (size_t)en * NH;
#pragma unroll
      for (int j = 0; j < 4; ++j) {
        const int col = nt * BN + wn + j * 16 + l15;
        float v = acc[i][j][reg] + b1[e * NH + col];
        v = 0.5f * v * (1.0f + erff(v * 0.70710678118654752f));
        hrow[col] = f2bf(v);
      }
    }
  }
}

__global__ __launch_bounds__(256, 2) void gemm2_fb(
    const unsigned short* __restrict__ h, const float* __restrict__ w2,
    const float* __restrict__ b2, const int* __restrict__ counts,
    const int* __restrict__ list, float* __restrict__ contrib) {
  int mt, ent;
  decode_bid_fb(blockIdx.x, NE * NNT2, mt, ent);
  const int e  = ent >> 3;
  const int nt = ent & 7;
  const int ne = counts[e];
  if (mt * BM >= ne) return;
  const int t = threadIdx.x;

  __shared__ __align__(16) unsigned char As[BM * BK * 2];
  __shared__ __align__(16) unsigned char Bs[BN * BK * 4];
  __shared__ int ent_s[BM];
  if (t < BM) {
    const int idx = mt * BM + t;
    ent_s[t] = (idx < ne) ? list[e * N_TOK + idx] : -1;
  }
  __syncthreads();

  const int lane = t & 63, w = t >> 6;
  const unsigned short* aP[4];
  const float* bP[8];
  unsigned char *aL[4], *bL[8];
  {
    const int l3 = lane >> 3, c7 = lane & 7;
#pragma unroll
    for (int p = 0; p < 4; ++p) {
      const int CI = w + 4 * p;
      const int R = 8 * CI + l3;
      const int c = c7 ^ (R & 7);
      const int en = ent_s[R];
      aP[p] = h + (size_t)(en >= 0 ? en : 0) * NH + c * 8;
      aL[p] = As + CI * 1024;
    }
    const int l4 = lane >> 4, c15 = lane & 15;
    const float* bbase = w2 + ((size_t)e * NO + (size_t)nt * BN) * NH;
#pragma unroll
    for (int q = 0; q < 8; ++q) {
      const int CI = w + 4 * q;
      const int R = 4 * CI + l4;
      const int c = c15 ^ (R & 15);
      bP[q] = bbase + (size_t)R * NH + c * 4;
      bL[q] = Bs + CI * 1024;
    }
  }

  const int wm = (w & 1) * 64, wn = (w >> 1) * 64;
  const int l15 = lane & 15, quad = lane >> 4;

  f32x4 acc[4][4];
#pragma unroll
  for (int i = 0; i < 4; ++i)
#pragma unroll
    for (int j = 0; j < 4; ++j) acc[i][j] = (f32x4){0.f, 0.f, 0.f, 0.f};

  for (int k0 = 0; k0 < NH; k0 += BK) {
#pragma unroll
    for (int p = 0; p < 4; ++p) glds16(aP[p] + k0, aL[p]);
#pragma unroll
    for (int q = 0; q < 8; ++q) glds16(bP[q] + k0, bL[q]);
    __syncthreads();
#pragma unroll
    for (int kk = 0; kk < BK; kk += 32) {
      short8 af[4], bfr[4];
#pragma unroll
      for (int i = 0; i < 4; ++i) {
        const int R = wm + i * 16 + l15;
        const int c0 = (kk >> 3) + quad;
        af[i] = *(const short8*)(As + R * 128 + ((c0 ^ (R & 7)) << 4));
      }
#pragma unroll
      for (int j = 0; j < 4; ++j) {
        const int R = wn + j * 16 + l15;
        const int c0 = (kk >> 2) + 2 * quad;
        const float4 f0 = *(const float4*)(Bs + R * 256 + ((c0 ^ (R & 15)) << 4));
        const float4 f1 = *(const float4*)(Bs + R * 256 + (((c0 + 1) ^ (R & 15)) << 4));
        bfr[j] = cvt8(f0, f1);
      }
#pragma unroll
      for (int i = 0; i < 4; ++i)
#pragma unroll
        for (int j = 0; j < 4; ++j)
          acc[i][j] = __builtin_amdgcn_mfma_f32_16x16x32_bf16(af[i], bfr[j], acc[i][j], 0, 0, 0);
    }
    lds_barrier();
  }

  const int r4 = quad * 4;
#pragma unroll
  for (int i = 0; i < 4; ++i) {
#pragma unroll
    for (int reg = 0; reg < 4; ++reg) {
      const int row = wm + i * 16 + r4 + reg;
      const int en = ent_s[row];
      if (en < 0) continue;
      float* crow = contrib + (size_t)en * NO;
#pragma unroll
      for (int j = 0; j < 4; ++j) {
        const int col = nt * BN + wn + j * 16 + l15;
        crow[col] = acc[i][j][reg] + b2[e * NO + col];
      }
    }
  }
}

__global__ __launch_bounds__(256) void combine_kernel(
    const float* __restrict__ contrib, const float* __restrict__ tkw,
    float* __restrict__ out) {
  const int gid = blockIdx.x * 256 + threadIdx.x;
  const int n = gid >> 8;
  const int c = (gid & 255) * 4;
  const float w0 = tkw[n * 2], w1 = tkw[n * 2 + 1];
  const float4 a = *(const float4*)(contrib + (size_t)(n * 2) * NO + c);
  const float4 b = *(const float4*)(contrib + (size_t)(n * 2 + 1) * NO + c);
  float4 o;
  o.x = w0 * a.x + w1 * b.x; o.y = w0 * a.y + w1 * b.y;
  o.z = w0 * a.z + w1 * b.z; o.w = w0 * a.w + w1 * b.w;
  *(float4*)(out + (size_t)n * NO + c) = o;
}

extern "C" void kernel_launch(void* const* d_in, const int* in_sizes, int n_in,
                              void* d_out, int out_size, void* d_ws, size_t ws_size,
                              hipStream_t stream) {
  const float* z  = (const float*)d_in[0];
  const float* rw = (const float*)d_in[1];
  const float* rb = (const float*)d_in[2];
  const float* w1 = (const float*)d_in[3];
  const float* b1 = (const float*)d_in[4];
  const float* w2 = (const float*)d_in[5];
  const float* b2 = (const float*)d_in[6];
  float* out = (float*)d_out;

  char* ws = (char*)d_ws;
  int*   counts = (int*)ws;                                    // 256 B
  int*   list   = (int*)(ws + 256);                            // 128 KB
  float* tkw    = (float*)(ws + 256 + 131072);                 // 16 KB
  unsigned short* zbf = (unsigned short*)(ws + 262144);        // 4 MB
  unsigned short* h = (unsigned short*)(ws + 262144 + 4194304);// 16 MB

  const size_t base = 262144 + 4194304 + 16777216;             // 21.2 MB
  const size_t w1b_sz = (size_t)NE * NH * DIM * 2;             // 64 MB
  const size_t w2b_sz = (size_t)NE * NO * NH * 2;              // 64 MB
  const size_t need_fast = base + w1b_sz + w2b_sz;             // ~148 MB

  hipMemsetAsync(counts, 0, NE * sizeof(int), stream);
  convert_z_kernel<<<(N_TOK * DIM / 8) / 256, 256, 0, stream>>>(z, zbf);
  router_kernel<<<N_TOK, 256, 0, stream>>>(z, rw, rb, counts, list, tkw);

  if (ws_size >= need_fast) {
    unsigned short* w1b = (unsigned short*)(ws + base);
    unsigned short* w2b = (unsigned short*)(ws + base + w1b_sz);
    hipMemsetAsync(out, 0, (size_t)N_TOK * NO * sizeof(float), stream);
    convert_w_kernel<<<(NE * NH * DIM / 8) / 256, 256, 0, stream>>>(w1, w1b);
    convert_w_kernel<<<(NE * NO * NH / 8) / 256, 256, 0, stream>>>(w2, w2b);
    gemm1_fast<<<2048, 256, 0, stream>>>(zbf, w1b, b1, counts, list, h);
    gemm2_fast<<<2048, 256, 0, stream>>>(h, w2b, b2, counts, list, tkw, out);
  } else {
    float* contrib = (float*)(ws + base);                      // 16 MB
    gemm1_fb<<<MT_LEVELS * NE * NNT1, 256, 0, stream>>>(zbf, w1, b1, counts, list, h);
    gemm2_fb<<<MT_LEVELS * NE * NNT2, 256, 0, stream>>>(h, w2, b2, counts, list, contrib);
    combine_kernel<<<(N_TOK * (NO / 4)) / 256, 256, 0, stream>>>(contrib, tkw, out);
  }
}

// Round 5
// 530.816 us; speedup vs baseline: 1.0072x; 1.0072x over previous
//
#include <hip/hip_runtime.h>
#include <hip/hip_bf16.h>
#include <math.h>

#define N_TOK 2048
#define DIM   1024
#define NE    16
#define NH    2048
#define NO    1024

typedef __attribute__((ext_vector_type(8))) short short8;
typedef __attribute__((ext_vector_type(4))) float f32x4;

__device__ __forceinline__ unsigned short f2bf(float f) {
  union { float f; unsigned u; } v; v.f = f;
  unsigned r = v.u + 0x7FFFu + ((v.u >> 16) & 1u);  // RNE
  return (unsigned short)(r >> 16);
}

__device__ __forceinline__ short8 pack8(float4 a, float4 b) {
  short8 r;
  r[0] = (short)f2bf(a.x); r[1] = (short)f2bf(a.y);
  r[2] = (short)f2bf(a.z); r[3] = (short)f2bf(a.w);
  r[4] = (short)f2bf(b.x); r[5] = (short)f2bf(b.y);
  r[6] = (short)f2bf(b.z); r[7] = (short)f2bf(b.w);
  return r;
}

__device__ __forceinline__ unsigned pkbf(float x, float y) {
  float2 f; f.x = x; f.y = y;
  __hip_bfloat162 b = __float22bfloat162_rn(f);     // v_cvt_pk_bf16_f32 (RNE)
  unsigned u; __builtin_memcpy(&u, &b, 4);
  return u;
}
__device__ __forceinline__ short8 cvt8(float4 a, float4 b) {
  union { short8 s; unsigned u[4]; } r;
  r.u[0] = pkbf(a.x, a.y); r.u[1] = pkbf(a.z, a.w);
  r.u[2] = pkbf(b.x, b.y); r.u[3] = pkbf(b.z, b.w);
  return r.s;
}

// async global->LDS, 16B/lane; LDS dest = wave-uniform base + lane*16 (m97/m104)
__device__ __forceinline__ void glds16(const void* g, void* l) {
  __builtin_amdgcn_global_load_lds(
      (const __attribute__((address_space(1))) void*)g,
      (__attribute__((address_space(3))) void*)l, 16, 0, 0);
}

// ---------------- Router: fp32 in, double accum, top-2 + renorm ----------------
__global__ __launch_bounds__(256) void router_kernel(
    const float* __restrict__ z, const float* __restrict__ rw,
    const float* __restrict__ rb, int* __restrict__ counts,
    int* __restrict__ list, float* __restrict__ tkw) {
  const int n = blockIdx.x;
  const int t = threadIdx.x;
  const int e = t >> 4, sub = t & 15;
  const float* zr = z + (size_t)n * DIM;
  const float* wr = rw + (size_t)e * DIM;
  double acc = 0.0;
#pragma unroll
  for (int i = 0; i < 16; ++i) {
    const int d = i * 64 + sub * 4;
    const float4 zv = *(const float4*)(zr + d);
    const float4 wv = *(const float4*)(wr + d);
    acc += (double)zv.x * wv.x + (double)zv.y * wv.y
         + (double)zv.z * wv.z + (double)zv.w * wv.w;
  }
  acc += __shfl_xor(acc, 8, 16);
  acc += __shfl_xor(acc, 4, 16);
  acc += __shfl_xor(acc, 2, 16);
  acc += __shfl_xor(acc, 1, 16);
  __shared__ double logits[NE];
  if (sub == 0) logits[e] = acc + (double)rb[e];
  __syncthreads();
  if (t == 0) {
    int i0 = -1, i1 = -1; double v0 = -1e300, v1 = -1e300;
    for (int i = 0; i < NE; ++i) {
      const double v = logits[i];
      if (v > v0) { v1 = v0; i1 = i0; v0 = v; i0 = i; }
      else if (v > v1) { v1 = v; i1 = i; }
    }
    const double w0 = 1.0 / (1.0 + exp(v1 - v0));
    tkw[n * 2 + 0] = (float)w0;
    tkw[n * 2 + 1] = (float)(1.0 - w0);
    const int p0 = atomicAdd(&counts[i0], 1); list[i0 * N_TOK + p0] = n * 2;
    const int p1 = atomicAdd(&counts[i1], 1); list[i1 * N_TOK + p1] = n * 2 + 1;
  }
}

// ---------------- fp32 -> bf16 converters ----------------
__global__ __launch_bounds__(256) void convert_z_kernel(
    const float* __restrict__ z, unsigned short* __restrict__ zbf) {
  const int i = (blockIdx.x * 256 + threadIdx.x) * 8;
  const float4 a = *(const float4*)(z + i);
  const float4 b = *(const float4*)(z + i + 4);
  *(short8*)(zbf + i) = pack8(a, b);
}

__global__ __launch_bounds__(256) void convert_w_kernel(
    const float* __restrict__ src, unsigned short* __restrict__ dst) {
  const size_t i = ((size_t)blockIdx.x * 256 + threadIdx.x) * 8;
  const float4 a = *(const float4*)(src + i);
  const float4 b = *(const float4*)(src + i + 4);
  *(short8*)(dst + i) = cvt8(a, b);
}

// =====================================================================
// Hybrid GEMMs: A (gathered, reused) via glds16 double-buffered LDS;
// B (bf16 weights) straight to registers, double-buffered one FULL
// K-step ahead (latency hidden across compute+barrier+issue of a step,
// drained by the one __syncthreads/step). BM=128, BN=64, BK=64.
// =====================================================================
#define BM 128
#define BK 64
#define BN 64
#define ASZ (BM * BK * 2)   // 16 KB

// One pipelined K-step. BU = B-regs for this step, BN_ = filled for next.
#define GSTEP(KT, NSTEP, BU, BN_)                                          \
  {                                                                        \
    if ((KT) + 1 < (NSTEP)) {                                              \
      const int k1 = ((KT) + 1) * BK;                                      \
      _Pragma("unroll")                                                    \
      for (int p = 0; p < 4; ++p)                                          \
        glds16(aP[p] + k1, aL[p] + (((KT) + 1) & 1) * ASZ);                \
      _Pragma("unroll")                                                    \
      for (int j = 0; j < 2; ++j) {                                        \
        BN_[j * 2 + 0] = *(const short8*)(bRow[j] + k1);                   \
        BN_[j * 2 + 1] = *(const short8*)(bRow[j] + k1 + 32);              \
      }                                                                    \
    }                                                                      \
    const unsigned char* Ac = As + ((KT) & 1) * ASZ;                       \
    _Pragma("unroll")                                                      \
    for (int kk2 = 0; kk2 < 2; ++kk2) {                                    \
      short8 af[4];                                                        \
      const int c0 = kk2 * 4 + quad;                                       \
      _Pragma("unroll")                                                    \
      for (int i = 0; i < 4; ++i) {                                        \
        const int R = wm + i * 16 + l15;                                   \
        af[i] = *(const short8*)(Ac + R * 128 + ((c0 ^ (R & 7)) << 4));    \
      }                                                                    \
      _Pragma("unroll")                                                    \
      for (int i = 0; i < 4; ++i)                                          \
        _Pragma("unroll")                                                  \
        for (int j = 0; j < 2; ++j)                                        \
          acc[i][j] = __builtin_amdgcn_mfma_f32_16x16x32_bf16(             \
              af[i], BU[j * 2 + kk2], acc[i][j], 0, 0, 0);                 \
    }                                                                      \
    __syncthreads();                                                       \
  }

// ---------------- GEMM1: h[slot] = gelu(zbf[tok] @ w1b^T + b1) -> bf16 --------
// grid 4096; active-first decode: bids 0..1023 are mt in {0,1} (always active
// for balanced routing); dead mt-levels trail.
__global__ __launch_bounds__(256, 3) void gemm1_kernel(
    const unsigned short* __restrict__ zbf, const unsigned short* __restrict__ w1b,
    const float* __restrict__ b1, const int* __restrict__ counts,
    const int* __restrict__ list, unsigned short* __restrict__ h) {
  const int bid = blockIdx.x;
  int mt, e, nt;
  if (bid < 1024) {
    mt = bid & 1;
    const int rest = bid >> 1;      // 0..511
    e = rest & 15; nt = rest >> 4;  // nt 0..31
  } else {
    const int t2 = bid - 1024;      // 0..3071
    mt = 2 + (t2 >> 9);             // 2..7
    const int r = t2 & 511;
    e = r & 15; nt = r >> 4;
  }
  const int ne = counts[e];
  if (mt * BM >= ne) return;
  const int t = threadIdx.x;

  __shared__ __align__(16) unsigned char As[2 * ASZ];   // 32 KB
  __shared__ int ent_s[BM];
  if (t < BM) {
    const int idx = mt * BM + t;
    ent_s[t] = (idx < ne) ? list[e * N_TOK + idx] : -1;
  }
  __syncthreads();

  const int lane = t & 63, w = t >> 6;
  const unsigned short* aP[4];
  unsigned char* aL[4];
  {
    const int l3 = lane >> 3, c7 = lane & 7;
#pragma unroll
    for (int p = 0; p < 4; ++p) {
      const int CI = w + 4 * p;               // 16 chunks of 8 rows x 128 B
      const int R = 8 * CI + l3;
      const int c = c7 ^ (R & 7);
      const int en = ent_s[R];
      aP[p] = zbf + (size_t)(en >= 0 ? (en >> 1) : 0) * DIM + c * 8;
      aL[p] = As + CI * 1024;
    }
  }
  const int wm = (w & 1) * 64, wn = (w >> 1) * 32;
  const int l15 = lane & 15, quad = lane >> 4;

  // B fragment rows: lane(l15,quad) holds row nt*64+wn+j*16+l15, k=quad*8..+8
  const unsigned short* bRow[2];
#pragma unroll
  for (int j = 0; j < 2; ++j)
    bRow[j] = w1b + ((size_t)e * NH + (size_t)(nt * BN + wn + j * 16 + l15)) * DIM + quad * 8;

  f32x4 acc[4][2];
#pragma unroll
  for (int i = 0; i < 4; ++i)
#pragma unroll
    for (int j = 0; j < 2; ++j) acc[i][j] = (f32x4){0.f, 0.f, 0.f, 0.f};

  short8 bA[4], bB[4];
  // prologue: tile 0 -> buf0 + Breg
#pragma unroll
  for (int p = 0; p < 4; ++p) glds16(aP[p], aL[p]);
#pragma unroll
  for (int j = 0; j < 2; ++j) {
    bA[j * 2 + 0] = *(const short8*)(bRow[j]);
    bA[j * 2 + 1] = *(const short8*)(bRow[j] + 32);
  }
  __syncthreads();

  for (int kt2 = 0; kt2 < 8; ++kt2) {
    GSTEP(kt2 * 2,     16, bA, bB);
    GSTEP(kt2 * 2 + 1, 16, bB, bA);
  }

  const int r4 = quad * 4;    // C/D: col=lane&15, row=quad*4+reg
#pragma unroll
  for (int i = 0; i < 4; ++i) {
#pragma unroll
    for (int reg = 0; reg < 4; ++reg) {
      const int row = wm + i * 16 + r4 + reg;
      const int en = ent_s[row];
      if (en < 0) continue;
      unsigned short* hrow = h + (size_t)en * NH;
#pragma unroll
      for (int j = 0; j < 2; ++j) {
        const int col = nt * BN + wn + j * 16 + l15;
        float v = acc[i][j][reg] + b1[e * NH + col];
        v = 0.5f * v * (1.0f + erff(v * 0.70710678118654752f));
        hrow[col] = f2bf(v);
      }
    }
  }
}

// ---------------- GEMM2 (+fused combine): out += tkw * (h @ w2b^T + b2) -------
// split-K x2 (16 steps per half); linear epilogue -> atomicAdd (r4-proven).
__global__ __launch_bounds__(256, 3) void gemm2_kernel(
    const unsigned short* __restrict__ h, const unsigned short* __restrict__ w2b,
    const float* __restrict__ b2, const int* __restrict__ counts,
    const int* __restrict__ list, const float* __restrict__ tkw,
    float* __restrict__ out) {
  const int bid = blockIdx.x;
  int mt, e, nt, ks;
  if (bid < 1024) {
    mt = bid & 1;
    ks = (bid >> 1) & 1;
    const int rest = bid >> 2;      // 0..255
    e = rest & 15; nt = rest >> 4;  // nt 0..15
  } else {
    const int t2 = bid - 1024;
    mt = 2 + (t2 >> 9);
    const int r = t2 & 511;
    ks = r & 1; e = (r >> 1) & 15; nt = r >> 5;
  }
  const int ne = counts[e];
  if (mt * BM >= ne) return;
  const int t = threadIdx.x;
  const int kbase = ks * (NH / 2);  // 0 or 1024

  __shared__ __align__(16) unsigned char As[2 * ASZ];
  __shared__ int ent_s[BM];
  if (t < BM) {
    const int idx = mt * BM + t;
    ent_s[t] = (idx < ne) ? list[e * N_TOK + idx] : -1;
  }
  __syncthreads();

  const int lane = t & 63, w = t >> 6;
  const unsigned short* aP[4];
  unsigned char* aL[4];
  {
    const int l3 = lane >> 3, c7 = lane & 7;
#pragma unroll
    for (int p = 0; p < 4; ++p) {
      const int CI = w + 4 * p;
      const int R = 8 * CI + l3;
      const int c = c7 ^ (R & 7);
      const int en = ent_s[R];
      aP[p] = h + (size_t)(en >= 0 ? en : 0) * NH + kbase + c * 8;
      aL[p] = As + CI * 1024;
    }
  }
  const int wm = (w & 1) * 64, wn = (w >> 1) * 32;
  const int l15 = lane & 15, quad = lane >> 4;

  const unsigned short* bRow[2];
#pragma unroll
  for (int j = 0; j < 2; ++j)
    bRow[j] = w2b + ((size_t)e * NO + (size_t)(nt * BN + wn + j * 16 + l15)) * NH + kbase + quad * 8;

  f32x4 acc[4][2];
#pragma unroll
  for (int i = 0; i < 4; ++i)
#pragma unroll
    for (int j = 0; j < 2; ++j) acc[i][j] = (f32x4){0.f, 0.f, 0.f, 0.f};

  short8 bA[4], bB[4];
#pragma unroll
  for (int p = 0; p < 4; ++p) glds16(aP[p], aL[p]);
#pragma unroll
  for (int j = 0; j < 2; ++j) {
    bA[j * 2 + 0] = *(const short8*)(bRow[j]);
    bA[j * 2 + 1] = *(const short8*)(bRow[j] + 32);
  }
  __syncthreads();

  for (int kt2 = 0; kt2 < 8; ++kt2) {
    GSTEP(kt2 * 2,     16, bA, bB);
    GSTEP(kt2 * 2 + 1, 16, bB, bA);
  }

  const int r4 = quad * 4;
#pragma unroll
  for (int i = 0; i < 4; ++i) {
#pragma unroll
    for (int reg = 0; reg < 4; ++reg) {
      const int row = wm + i * 16 + r4 + reg;
      const int en = ent_s[row];
      if (en < 0) continue;
      const float wgt = tkw[en];
      float* orow = out + (size_t)(en >> 1) * NO;
#pragma unroll
      for (int j = 0; j < 2; ++j) {
        const int col = nt * BN + wn + j * 16 + l15;
        float v = wgt * acc[i][j][reg];
        if (ks == 0) v += wgt * b2[e * NO + col];
        atomicAdd(&orow[col], v);
      }
    }
  }
}

extern "C" void kernel_launch(void* const* d_in, const int* in_sizes, int n_in,
                              void* d_out, int out_size, void* d_ws, size_t ws_size,
                              hipStream_t stream) {
  const float* z  = (const float*)d_in[0];
  const float* rw = (const float*)d_in[1];
  const float* rb = (const float*)d_in[2];
  const float* w1 = (const float*)d_in[3];
  const float* b1 = (const float*)d_in[4];
  const float* w2 = (const float*)d_in[5];
  const float* b2 = (const float*)d_in[6];
  float* out = (float*)d_out;

  char* ws = (char*)d_ws;
  int*   counts = (int*)ws;                                    // 256 B
  int*   list   = (int*)(ws + 256);                            // 128 KB
  float* tkw    = (float*)(ws + 256 + 131072);                 // 16 KB
  unsigned short* zbf = (unsigned short*)(ws + 262144);        // 4 MB
  unsigned short* h = (unsigned short*)(ws + 262144 + 4194304);// 16 MB
  const size_t base = 262144 + 4194304 + 16777216;             // ~21.2 MB
  unsigned short* w1b = (unsigned short*)(ws + base);          // 64 MB
  unsigned short* w2b = (unsigned short*)(ws + base + (size_t)NE * NH * DIM * 2); // 64 MB

  hipMemsetAsync(counts, 0, NE * sizeof(int), stream);
  hipMemsetAsync(out, 0, (size_t)N_TOK * NO * sizeof(float), stream);
  convert_z_kernel<<<(N_TOK * DIM / 8) / 256, 256, 0, stream>>>(z, zbf);
  router_kernel<<<N_TOK, 256, 0, stream>>>(z, rw, rb, counts, list, tkw);
  convert_w_kernel<<<(int)(((size_t)NE * NH * DIM / 8) / 256), 256, 0, stream>>>(w1, w1b);
  convert_w_kernel<<<(int)(((size_t)NE * NO * NH / 8) / 256), 256, 0, stream>>>(w2, w2b);
  gemm1_kernel<<<4096, 256, 0, stream>>>(zbf, w1b, b1, counts, list, h);
  gemm2_kernel<<<4096, 256, 0, stream>>>(h, w2b, b2, counts, list, tkw, out);
}